// Round 16
// baseline (2325.047 us; speedup 1.0000x reference)
//
#include <hip/hip_runtime.h>
#include <hip/hip_bf16.h>

#define H 1024
#define T 2048
#define B 32
#define BM 128        // rows per block
#define BN 256        // cols per block
#define NCOLT 4       // col tiles
#define BK 32         // k per chunk
#define NCH 32        // H / BK

typedef __attribute__((ext_vector_type(8))) __bf16 bf16x8;
typedef __attribute__((ext_vector_type(16))) float f32x16;
typedef __attribute__((ext_vector_type(8))) unsigned short u16x8;

__device__ __forceinline__ unsigned short f2bf(float f) {
    unsigned int x = __float_as_uint(f);
    x += 0x7fffu + ((x >> 16) & 1u);
    return (unsigned short)(x >> 16);
}

__device__ __forceinline__ float fast_tanh(float x) {
    float t = __expf(2.0f * x);
    return 1.0f - 2.0f * __builtin_amdgcn_rcpf(t + 1.0f);
}

__device__ __forceinline__ void gload16(const void* g, void* l) {
    __builtin_amdgcn_global_load_lds((const __attribute__((address_space(1))) void*)g,
                                     (__attribute__((address_space(3))) void*)l, 16, 0, 0);
}

// Pack W2 = W[:, H:2H] into bf16, layout Wp[kg][n][8] (kg = k>>3), 16B per (kg,n)
__global__ __launch_bounds__(256) void prep_w_kernel(const float* __restrict__ W,
                                                     unsigned short* __restrict__ Wp) {
    int gid = blockIdx.x * 256 + threadIdx.x;
    int n = gid & (H - 1);
    int kg = gid >> 10;
    const float* srcp = W + (size_t)n * (2 * H) + H + kg * 8;
    float4 f0 = *(const float4*)(srcp);
    float4 f1 = *(const float4*)(srcp + 4);
    u16x8 o;
    o[0] = f2bf(f0.x); o[1] = f2bf(f0.y); o[2] = f2bf(f0.z); o[3] = f2bf(f0.w);
    o[4] = f2bf(f1.x); o[5] = f2bf(f1.y); o[6] = f2bf(f1.z); o[7] = f2bf(f1.w);
    *(u16x8*)(Wp + (size_t)gid * 8) = o;
}

// hp[b][h] = sum_d hidden[b][d]*W[h][d] + bias[h], k-split x4 + shuffle reduce
__global__ __launch_bounds__(256) void prep_hp_kernel(const float* __restrict__ hidden,
                                                      const float* __restrict__ W,
                                                      const float* __restrict__ bias,
                                                      float* __restrict__ hp) {
    int b = blockIdx.y;
    int t = threadIdx.x;
    int h = blockIdx.x * 64 + (t >> 2);
    int kq = t & 3;
    const float* hid = hidden + (size_t)b * H + kq * 256;
    const float* wr = W + (size_t)h * (2 * H) + kq * 256;
    float acc = 0.f;
#pragma unroll 4
    for (int d = 0; d < 256; d += 4) {
        float4 wv = *(const float4*)(wr + d);
        float4 hv = *(const float4*)(hid + d);
        acc += wv.x * hv.x + wv.y * hv.y + wv.z * hv.z + wv.w * hv.w;
    }
    acc += __shfl_xor(acc, 1);
    acc += __shfl_xor(acc, 2);
    if (kq == 0) hp[(size_t)b * H + h] = acc + bias[h];
}

#define MFMA32(A, Bv, C) __builtin_amdgcn_mfma_f32_32x32x16_bf16(A, Bv, C, 0, 0, 0)

// Small-block/high-residency fused kernel (m97 regime: 3 blocks/CU, cross-block overlap):
// 256 thr = 4 waves; wave w = 128 rows x 64 cols (cols w*64..w*64+64), acc = 8 x f32x16.
// A: enc fp32, 2-chunk-ahead reg loads (static ping-pong sets) -> cvt -> bf16 LDS dbuf.
// B: Wp bf16 via global_load_lds w16, 1 chunk ahead; wave w fills page w (4 colblk calls).
// LDS page-major (page = 8-k group): A addr = p*2048 + row*16; B addr = p*4096 + col*16
// (row/col-contiguous reads & writes -> conflict-free without swizzle).
__global__ __launch_bounds__(256, 3) void energy_kernel(const float* __restrict__ enc,
                                                        const float* __restrict__ hp,
                                                        const float* __restrict__ vvec,
                                                        const unsigned short* __restrict__ Wp,
                                                        float* __restrict__ sc_part) {
    __shared__ __align__(16) unsigned short Abuf[2][BM * BK];   // 2 x 8 KB
    __shared__ __align__(16) unsigned short Bbuf[2][BK * BN];   // 2 x 16 KB
    __shared__ float scpart[4][BM];                             // 2 KB

    const int tid = threadIdx.x;
    const int t0 = blockIdx.x * BM;
    const int colt = blockIdx.y;
    const int b = blockIdx.z;
    const int c0 = colt * BN;
    const int wave = tid >> 6;
    const int lane = tid & 63;
    const int l31 = lane & 31;
    const int hi = lane >> 5;

    // ---- A staging map: thread -> (row = tid>>1, khalf = tid&1), 64B fp32 -> 32B bf16
    const int st_row = tid >> 1;
    const int st_kh = tid & 1;
    const float* st_src = enc + ((size_t)b * T + t0 + st_row) * H + st_kh * 16;
    char* Ab0 = (char*)&Abuf[0][0];
    char* st_d0 = Ab0 + (st_kh * 2) * 2048 + st_row * 16;       // page 2*kh
    char* st_d1 = Ab0 + (st_kh * 2 + 1) * 2048 + st_row * 16;   // page 2*kh+1

    // ---- B DMA map: wave w fills page w; 4 colblk calls of 64 lanes x 16B
    char* Bb0 = (char*)&Bbuf[0][0];
    char* bdst = Bb0 + wave * 4096 + lane * 16;
    const unsigned short* bsrc = Wp + (size_t)wave * (H * 8) + (size_t)(c0 + lane) * 8;

    f32x16 acc[4][2];
#pragma unroll
    for (int rg = 0; rg < 4; ++rg)
#pragma unroll
        for (int cg = 0; cg < 2; ++cg)
#pragma unroll
            for (int i = 0; i < 16; ++i) acc[rg][cg][i] = 0.f;

#define STAGE_A_WRITE(FA0, FA1, FA2, FA3, BUFSEL)                              \
    {                                                                          \
        u16x8 o0, o1;                                                          \
        o0[0] = f2bf(FA0.x); o0[1] = f2bf(FA0.y); o0[2] = f2bf(FA0.z); o0[3] = f2bf(FA0.w); \
        o0[4] = f2bf(FA1.x); o0[5] = f2bf(FA1.y); o0[6] = f2bf(FA1.z); o0[7] = f2bf(FA1.w); \
        o1[0] = f2bf(FA2.x); o1[1] = f2bf(FA2.y); o1[2] = f2bf(FA2.z); o1[3] = f2bf(FA2.w); \
        o1[4] = f2bf(FA3.x); o1[5] = f2bf(FA3.y); o1[6] = f2bf(FA3.z); o1[7] = f2bf(FA3.w); \
        *(u16x8*)(st_d0 + (BUFSEL) * 8192) = o0;                               \
        *(u16x8*)(st_d1 + (BUFSEL) * 8192) = o1;                               \
    }

#define LOAD_A(FA0, FA1, FA2, FA3, CH)                                         \
    {                                                                          \
        const float* p_ = st_src + (size_t)((CH) & 31) * BK;                   \
        FA0 = *(const float4*)(p_);                                            \
        FA1 = *(const float4*)(p_ + 4);                                        \
        FA2 = *(const float4*)(p_ + 8);                                        \
        FA3 = *(const float4*)(p_ + 12);                                       \
    }

#define DMA_B(CH)                                                              \
    {                                                                          \
        const unsigned short* bs_ = bsrc + (size_t)(((CH) & 31) * 4) * (H * 8);\
        char* bd_ = bdst + (((CH) & 1)) * 16384;                               \
        gload16(bs_, bd_);                                                     \
        gload16(bs_ + 512, bd_ + 1024);                                        \
        gload16(bs_ + 1024, bd_ + 2048);                                       \
        gload16(bs_ + 1536, bd_ + 3072);                                       \
    }

#define COMPUTE(J)                                                             \
    {                                                                          \
        const char* Ab_ = Ab0 + ((J) & 1) * 8192;                              \
        const char* Bb_ = Bb0 + ((J) & 1) * 16384;                             \
        _Pragma("unroll")                                                      \
        for (int t = 0; t < 2; ++t) {                                          \
            const int ks = t * 2 + hi;                                         \
            const char* ap = Ab_ + ks * 2048;                                  \
            bf16x8 a0 = *(const bf16x8*)(ap + (0 * 32 + l31) * 16);            \
            bf16x8 a1 = *(const bf16x8*)(ap + (1 * 32 + l31) * 16);            \
            bf16x8 a2 = *(const bf16x8*)(ap + (2 * 32 + l31) * 16);            \
            bf16x8 a3 = *(const bf16x8*)(ap + (3 * 32 + l31) * 16);            \
            const char* bp = Bb_ + ks * 4096 + (wave * 64 + l31) * 16;         \
            bf16x8 b0 = *(const bf16x8*)(bp);                                  \
            bf16x8 b1 = *(const bf16x8*)(bp + 512);                            \
            __builtin_amdgcn_s_setprio(1);                                     \
            acc[0][0] = MFMA32(a0, b0, acc[0][0]);                             \
            acc[0][1] = MFMA32(a0, b1, acc[0][1]);                             \
            acc[1][0] = MFMA32(a1, b0, acc[1][0]);                             \
            acc[1][1] = MFMA32(a1, b1, acc[1][1]);                             \
            acc[2][0] = MFMA32(a2, b0, acc[2][0]);                             \
            acc[2][1] = MFMA32(a2, b1, acc[2][1]);                             \
            acc[3][0] = MFMA32(a3, b0, acc[3][0]);                             \
            acc[3][1] = MFMA32(a3, b1, acc[3][1]);                             \
            __builtin_amdgcn_s_setprio(0);                                     \
        }                                                                      \
    }

    float4 fx0, fx1, fx2, fx3;   // A data for odd chunks (loaded 2 ahead)
    float4 fy0, fy1, fy2, fy3;   // A data for even chunks

    // ---- prologue: stage A0 directly; load A1 into fx; DMA B0 ----
    {
        float4 g0, g1, g2, g3;
        LOAD_A(g0, g1, g2, g3, 0)
        STAGE_A_WRITE(g0, g1, g2, g3, 0)
    }
    LOAD_A(fx0, fx1, fx2, fx3, 1)
    DMA_B(0)
    __syncthreads();

    // main loop: 2 chunks per iteration (static ping-pong of A reg sets)
    for (int i = 0; i < NCH / 2; ++i) {
        const int e = 2 * i;
        // chunk e (even): reads buf[0]
        DMA_B(e + 1);
        LOAD_A(fy0, fy1, fy2, fy3, e + 2)
        COMPUTE(e)
        STAGE_A_WRITE(fx0, fx1, fx2, fx3, 1)   // data for chunk e+1 -> buf[1]
        __syncthreads();
        // chunk e+1 (odd): reads buf[1]
        DMA_B(e + 2);
        LOAD_A(fx0, fx1, fx2, fx3, e + 3)
        COMPUTE(e + 1)
        STAGE_A_WRITE(fy0, fy1, fy2, fy3, 0)   // data for chunk e+2 -> buf[0]
        __syncthreads();
    }
#undef COMPUTE
#undef DMA_B
#undef LOAD_A
#undef STAGE_A_WRITE

    // ---- fused epilogue: tanh + v-dot over this wave's 64 cols ----
    const size_t bH = (size_t)b * H;
    const int col0 = c0 + wave * 64 + l31;
    const int col1 = col0 + 32;
    const float hp0 = hp[bH + col0], hp1 = hp[bH + col1];
    const float v0 = vvec[col0], v1 = vvec[col1];
    float psc[4][16];
#pragma unroll
    for (int rg = 0; rg < 4; ++rg)
#pragma unroll
        for (int r = 0; r < 16; ++r)
            psc[rg][r] = v0 * fast_tanh(acc[rg][0][r] + hp0) +
                         v1 * fast_tanh(acc[rg][1][r] + hp1);

#pragma unroll
    for (int rg = 0; rg < 4; ++rg)
#pragma unroll
        for (int r = 0; r < 16; ++r) {
            float s = psc[rg][r];
            s += __shfl_xor(s, 1);
            s += __shfl_xor(s, 2);
            s += __shfl_xor(s, 4);
            s += __shfl_xor(s, 8);
            s += __shfl_xor(s, 16);
            psc[rg][r] = s;
        }
    if (l31 == 0) {
#pragma unroll
        for (int rg = 0; rg < 4; ++rg)
#pragma unroll
            for (int r = 0; r < 16; ++r) {
                int m = rg * 32 + (r & 3) + 8 * (r >> 2) + 4 * hi;
                scpart[wave][m] = psc[rg][r];
            }
    }
    __syncthreads();
    if (tid < BM) {
        float s = scpart[0][tid] + scpart[1][tid] + scpart[2][tid] + scpart[3][tid];
        sc_part[((size_t)colt * B + b) * T + t0 + tid] = s;
    }
}

__global__ __launch_bounds__(256) void softmax_kernel(const float* __restrict__ sc,
                                                      float* __restrict__ out) {
    int b = blockIdx.x;
    int tid = threadIdx.x;
    int wave = tid >> 6, lane = tid & 63;
    float vals[8];
    float m = -1e30f;
#pragma unroll
    for (int i = 0; i < 8; ++i) {
        int idx = tid + 256 * i;
        float s = 0.f;
#pragma unroll
        for (int p = 0; p < NCOLT; ++p) s += sc[((size_t)p * B + b) * T + idx];
        vals[i] = s;
        m = fmaxf(m, s);
    }
#pragma unroll
    for (int s = 1; s < 64; s <<= 1) m = fmaxf(m, __shfl_xor(m, s));
    __shared__ float red[4];
    __shared__ float red2[4];
    if (lane == 0) red[wave] = m;
    __syncthreads();
    m = fmaxf(fmaxf(red[0], red[1]), fmaxf(red[2], red[3]));
    float sum = 0.f;
#pragma unroll
    for (int i = 0; i < 8; ++i) { vals[i] = expf(vals[i] - m); sum += vals[i]; }
#pragma unroll
    for (int s = 1; s < 64; s <<= 1) sum += __shfl_xor(sum, s);
    if (lane == 0) red2[wave] = sum;
    __syncthreads();
    sum = red2[0] + red2[1] + red2[2] + red2[3];
    float inv = 1.0f / sum;
#pragma unroll
    for (int i = 0; i < 8; ++i) out[(size_t)b * T + tid + 256 * i] = vals[i] * inv;
}

extern "C" void kernel_launch(void* const* d_in, const int* in_sizes, int n_in,
                              void* d_out, int out_size, void* d_ws, size_t ws_size,
                              hipStream_t stream) {
    (void)in_sizes; (void)n_in; (void)out_size; (void)ws_size;
    const float* hidden = (const float*)d_in[0];   // [1,B,H]
    const float* enc    = (const float*)d_in[1];   // [B,T,H]
    const float* W      = (const float*)d_in[2];   // [H,2H]
    const float* bias   = (const float*)d_in[3];   // [H]
    const float* v      = (const float*)d_in[4];   // [H]
    float* out = (float*)d_out;                    // [B,1,T]

    unsigned short* Wp = (unsigned short*)d_ws;                               // 2 MB
    float* hp = (float*)((char*)d_ws + 2 * 1024 * 1024);                      // 128 KB
    float* sc = (float*)((char*)d_ws + 2 * 1024 * 1024 + 128 * 1024);         // 1 MB (4 partials)

    prep_w_kernel<<<dim3(512), dim3(256), 0, stream>>>(W, Wp);
    prep_hp_kernel<<<dim3(16, B), dim3(256), 0, stream>>>(hidden, W, bias, hp);
    energy_kernel<<<dim3(T / BM, NCOLT, B), dim3(256), 0, stream>>>(enc, hp, v, Wp, sc);
    softmax_kernel<<<dim3(B), dim3(256), 0, stream>>>(sc, out);
}

// Round 17
// 254.140 us; speedup vs baseline: 9.1487x; 9.1487x over previous
//
#include <hip/hip_runtime.h>
#include <hip/hip_bf16.h>

#define H 1024
#define T 2048
#define B 32
#define BM 64         // rows per block (t-tile)
#define BKC 128       // k per LDS chunk
#define NCHUNK 8      // H / BKC

typedef __attribute__((ext_vector_type(8))) __bf16 bf16x8;
typedef __attribute__((ext_vector_type(16))) float f32x16;
typedef __attribute__((ext_vector_type(8))) unsigned short u16x8;

__device__ __forceinline__ unsigned short f2bf(float f) {
    unsigned int x = __float_as_uint(f);
    x += 0x7fffu + ((x >> 16) & 1u);
    return (unsigned short)(x >> 16);
}

__device__ __forceinline__ float fast_tanh(float x) {
    float t = __expf(2.0f * x);
    return 1.0f - 2.0f * __builtin_amdgcn_rcpf(t + 1.0f);
}

// Pack W2 = W[:, H:2H] into bf16, layout Wp[kg][n][8] (kg = k>>3), 16B per (kg,n)
__global__ __launch_bounds__(256) void prep_w_kernel(const float* __restrict__ W,
                                                     unsigned short* __restrict__ Wp) {
    int gid = blockIdx.x * 256 + threadIdx.x;   // 131072 total
    int n = gid & (H - 1);
    int kg = gid >> 10;                          // 0..127
    const float* srcp = W + (size_t)n * (2 * H) + H + kg * 8;
    float4 f0 = *(const float4*)(srcp);
    float4 f1 = *(const float4*)(srcp + 4);
    u16x8 o;
    o[0] = f2bf(f0.x); o[1] = f2bf(f0.y); o[2] = f2bf(f0.z); o[3] = f2bf(f0.w);
    o[4] = f2bf(f1.x); o[5] = f2bf(f1.y); o[6] = f2bf(f1.z); o[7] = f2bf(f1.w);
    *(u16x8*)(Wp + (size_t)gid * 8) = o;
}

// hp[b][h] = sum_d hidden[b][d]*W[h][d] + bias[h], k-split x4 + shuffle reduce
__global__ __launch_bounds__(256) void prep_hp_kernel(const float* __restrict__ hidden,
                                                      const float* __restrict__ W,
                                                      const float* __restrict__ bias,
                                                      float* __restrict__ hp) {
    int b = blockIdx.y;
    int t = threadIdx.x;
    int h = blockIdx.x * 64 + (t >> 2);
    int kq = t & 3;
    const float* hid = hidden + (size_t)b * H + kq * 256;
    const float* wr = W + (size_t)h * (2 * H) + kq * 256;
    float acc = 0.f;
#pragma unroll 4
    for (int d = 0; d < 256; d += 4) {
        float4 wv = *(const float4*)(wr + d);
        float4 hv = *(const float4*)(hid + d);
        acc += wv.x * hv.x + wv.y * hv.y + wv.z * hv.z + wv.w * hv.w;
    }
    acc += __shfl_xor(acc, 1);
    acc += __shfl_xor(acc, 2);
    if (kq == 0) hp[(size_t)b * H + h] = acc + bias[h];
}

#define MFMA32(A, Bv, C) __builtin_amdgcn_mfma_f32_32x32x16_bf16(A, Bv, C, 0, 0, 0)

// Exact R10 structure, ONE change: B rolling prefetch depth 2 -> 4 (per-wave MLP x2).
// block = (64-row t-tile, b), 1024 thr = 16 waves; wave w owns cols [64w,64w+64).
// A: enc fp32 read once, reg-staged -> bf16 LDS, double-buffered; stage-issue at chunk
// top, ds_write + __syncthreads at chunk end (best-measured R10 pattern).
// B: Wp bf16 from L2, branchless wrapped depth-4 rolling prefetch: at STEP KI of chunk
// j, slot KI&3 holds nit = 8j+KI; reload (nit+4)&63 (wrap keeps loads unconditional;
// wrapped tail loads never consumed -> harmless).
// LDS layout (proven 0-conflict): page ks (0..15) -> ks*1024 + ((row^(ks&7))<<4).
__global__ __launch_bounds__(1024, 4) void energy_kernel(const float* __restrict__ enc,
                                                         const float* __restrict__ hp,
                                                         const float* __restrict__ vvec,
                                                         const unsigned short* __restrict__ Wp,
                                                         float* __restrict__ scores) {
    __shared__ __align__(16) unsigned short Abuf[2][BM * BKC];  // 2 x 16 KB
    __shared__ float scpart[16][BM];                            // 4 KB

    const int tid = threadIdx.x;
    const int b = blockIdx.y;
    const int t0 = blockIdx.x * BM;
    const int wave = tid >> 6;
    const int lane = tid & 63;
    const int l31 = lane & 31;
    const int hi = lane >> 5;

    // staging: thread -> (row = tid>>4 in 0..63, kf = tid&15); 32B fp32 -> 16B bf16
    const int st_row = tid >> 4;
    const int st_kf = tid & 15;
    const float* st_src = enc + ((size_t)b * T + t0 + st_row) * H + st_kf * 8;
    char* Ab0 = (char*)&Abuf[0][0];
    char* st_dst = Ab0 + st_kf * 1024 + (((st_row ^ (st_kf & 7))) << 4);

    // B stream: k-step nit (0..63): page kg = nit*2 + hi; col = wave*64 + {l31, l31+32}
    const unsigned short* wp_base = Wp + (size_t)(wave * 64 + l31) * 8 + (size_t)hi * (H * 8);

    f32x16 acc00, acc01, acc10, acc11;
#pragma unroll
    for (int i = 0; i < 16; ++i) { acc00[i] = 0.f; acc01[i] = 0.f; acc10[i] = 0.f; acc11[i] = 0.f; }

    const int rv0 = l31;        // a0 rows 0..31
    const int rv1 = 32 + l31;   // a1 rows 32..63

    // ---- prologue: stage chunk 0; preload B nit=0..3 (depth-4) ----
    {
        float4 f0 = *(const float4*)(st_src);
        float4 f1 = *(const float4*)(st_src + 4);
        u16x8 o;
        o[0] = f2bf(f0.x); o[1] = f2bf(f0.y); o[2] = f2bf(f0.z); o[3] = f2bf(f0.w);
        o[4] = f2bf(f1.x); o[5] = f2bf(f1.y); o[6] = f2bf(f1.z); o[7] = f2bf(f1.w);
        *(u16x8*)st_dst = o;
    }
    bf16x8 bA0 = *(const bf16x8*)(wp_base);
    bf16x8 bA1 = *(const bf16x8*)(wp_base + 256);
    bf16x8 bB0 = *(const bf16x8*)(wp_base + (size_t)1 * (H * 16));
    bf16x8 bB1 = *(const bf16x8*)(wp_base + (size_t)1 * (H * 16) + 256);
    bf16x8 bC0 = *(const bf16x8*)(wp_base + (size_t)2 * (H * 16));
    bf16x8 bC1 = *(const bf16x8*)(wp_base + (size_t)2 * (H * 16) + 256);
    bf16x8 bD0 = *(const bf16x8*)(wp_base + (size_t)3 * (H * 16));
    bf16x8 bD1 = *(const bf16x8*)(wp_base + (size_t)3 * (H * 16) + 256);
    __syncthreads();

    // Rolling invariant (depth-4): at STEP KI of chunk j, slot holds nit = 8j+KI;
    // reload (nit+4)&63 into the same slot.
#define STEP(KI, C0, C1)                                                       \
    {                                                                          \
        const int ks = (KI) * 2 + hi;                                          \
        const char* ap = Ab + ks * 1024;                                       \
        bf16x8 a0 = *(const bf16x8*)(ap + ((rv0 ^ (ks & 7)) << 4));            \
        bf16x8 a1 = *(const bf16x8*)(ap + ((rv1 ^ (ks & 7)) << 4));            \
        __builtin_amdgcn_s_setprio(1);                                         \
        acc00 = MFMA32(a0, C0, acc00);                                         \
        acc01 = MFMA32(a0, C1, acc01);                                         \
        acc10 = MFMA32(a1, C0, acc10);                                         \
        acc11 = MFMA32(a1, C1, acc11);                                         \
        __builtin_amdgcn_s_setprio(0);                                         \
        const int nitw = (j * 8 + (KI) + 4) & 63;                              \
        const unsigned short* bp = wp_base + (size_t)nitw * (H * 16);          \
        C0 = *(const bf16x8*)(bp);                                             \
        C1 = *(const bf16x8*)(bp + 256);                                       \
    }

    for (int j = 0; j < NCHUNK; ++j) {
        // issue next chunk's A loads early (T14: load-early, write-late)
        float4 f0, f1;
        const bool pfA = (j < NCHUNK - 1);
        if (pfA) {
            const float* p = st_src + (j + 1) * BKC;
            f0 = *(const float4*)(p);
            f1 = *(const float4*)(p + 4);
        }
        const char* Ab = Ab0 + (j & 1) * 16384;
        STEP(0, bA0, bA1)
        STEP(1, bB0, bB1)
        STEP(2, bC0, bC1)
        STEP(3, bD0, bD1)
        STEP(4, bA0, bA1)
        STEP(5, bB0, bB1)
        STEP(6, bC0, bC1)
        STEP(7, bD0, bD1)
        if (pfA) {
            u16x8 o;
            o[0] = f2bf(f0.x); o[1] = f2bf(f0.y); o[2] = f2bf(f0.z); o[3] = f2bf(f0.w);
            o[4] = f2bf(f1.x); o[5] = f2bf(f1.y); o[6] = f2bf(f1.z); o[7] = f2bf(f1.w);
            *(u16x8*)(st_dst + ((j + 1) & 1) * 16384) = o;
        }
        __syncthreads();
    }
#undef STEP

    // ---- fused epilogue: tanh + v-dot over this wave's 64 cols ----
    const size_t bH = (size_t)b * H;
    const int col0 = wave * 64 + l31;
    const int col1 = col0 + 32;
    const float hp0 = hp[bH + col0], hp1 = hp[bH + col1];
    const float v0 = vvec[col0], v1 = vvec[col1];
    float psc[2][16];
#pragma unroll
    for (int r = 0; r < 16; ++r) {
        psc[0][r] = v0 * fast_tanh(acc00[r] + hp0) + v1 * fast_tanh(acc01[r] + hp1);
        psc[1][r] = v0 * fast_tanh(acc10[r] + hp0) + v1 * fast_tanh(acc11[r] + hp1);
    }

#pragma unroll
    for (int rg = 0; rg < 2; ++rg)
#pragma unroll
        for (int r = 0; r < 16; ++r) {
            float s = psc[rg][r];
            s += __shfl_xor(s, 1);
            s += __shfl_xor(s, 2);
            s += __shfl_xor(s, 4);
            s += __shfl_xor(s, 8);
            s += __shfl_xor(s, 16);
            psc[rg][r] = s;
        }
    if (l31 == 0) {
#pragma unroll
        for (int rg = 0; rg < 2; ++rg)
#pragma unroll
            for (int r = 0; r < 16; ++r) {
                int m = rg * 32 + (r & 3) + 8 * (r >> 2) + 4 * hi;
                scpart[wave][m] = psc[rg][r];
            }
    }
    __syncthreads();
    if (tid < BM) {
        float s = 0.f;
#pragma unroll
        for (int w = 0; w < 16; ++w) s += scpart[w][tid];
        scores[(size_t)b * T + t0 + tid] = s;
    }
}

__global__ __launch_bounds__(256) void softmax_kernel(const float* __restrict__ sc,
                                                      float* __restrict__ out) {
    int b = blockIdx.x;
    int tid = threadIdx.x;
    int wave = tid >> 6, lane = tid & 63;
    const float* row = sc + (size_t)b * T;
    float vals[8];
    float m = -1e30f;
#pragma unroll
    for (int i = 0; i < 8; ++i) { vals[i] = row[tid + 256 * i]; m = fmaxf(m, vals[i]); }
#pragma unroll
    for (int s = 1; s < 64; s <<= 1) m = fmaxf(m, __shfl_xor(m, s));
    __shared__ float red[4];
    __shared__ float red2[4];
    if (lane == 0) red[wave] = m;
    __syncthreads();
    m = fmaxf(fmaxf(red[0], red[1]), fmaxf(red[2], red[3]));
    float sum = 0.f;
#pragma unroll
    for (int i = 0; i < 8; ++i) { vals[i] = expf(vals[i] - m); sum += vals[i]; }
#pragma unroll
    for (int s = 1; s < 64; s <<= 1) sum += __shfl_xor(sum, s);
    if (lane == 0) red2[wave] = sum;
    __syncthreads();
    sum = red2[0] + red2[1] + red2[2] + red2[3];
    float inv = 1.0f / sum;
#pragma unroll
    for (int i = 0; i < 8; ++i) out[(size_t)b * T + tid + 256 * i] = vals[i] * inv;
}

extern "C" void kernel_launch(void* const* d_in, const int* in_sizes, int n_in,
                              void* d_out, int out_size, void* d_ws, size_t ws_size,
                              hipStream_t stream) {
    (void)in_sizes; (void)n_in; (void)out_size; (void)ws_size;
    const float* hidden = (const float*)d_in[0];   // [1,B,H]
    const float* enc    = (const float*)d_in[1];   // [B,T,H]
    const float* W      = (const float*)d_in[2];   // [H,2H]
    const float* bias   = (const float*)d_in[3];   // [H]
    const float* v      = (const float*)d_in[4];   // [H]
    float* out = (float*)d_out;                    // [B,1,T]

    unsigned short* Wp = (unsigned short*)d_ws;                               // 2 MB
    float* hp = (float*)((char*)d_ws + 2 * 1024 * 1024);                      // 128 KB
    float* sc = (float*)((char*)d_ws + 2 * 1024 * 1024 + 128 * 1024);         // 256 KB

    prep_w_kernel<<<dim3(512), dim3(256), 0, stream>>>(W, Wp);
    prep_hp_kernel<<<dim3(16, B), dim3(256), 0, stream>>>(hidden, W, bias, hp);
    energy_kernel<<<dim3(T / BM, B), dim3(1024), 0, stream>>>(enc, hp, v, Wp, sc);
    softmax_kernel<<<dim3(B), dim3(256), 0, stream>>>(sc, out);
}

// Round 18
// 226.750 us; speedup vs baseline: 10.2538x; 1.1208x over previous
//
#include <hip/hip_runtime.h>
#include <hip/hip_bf16.h>

#define H 1024
#define T 2048
#define B 32
#define BM 64         // rows per block (t-tile)
#define BKC 128       // k per LDS chunk
#define NCHUNK 8      // H / BKC

typedef __attribute__((ext_vector_type(8))) __bf16 bf16x8;
typedef __attribute__((ext_vector_type(16))) float f32x16;
typedef __attribute__((ext_vector_type(8))) unsigned short u16x8;

__device__ __forceinline__ unsigned short f2bf(float f) {
    unsigned int x = __float_as_uint(f);
    x += 0x7fffu + ((x >> 16) & 1u);
    return (unsigned short)(x >> 16);
}

__device__ __forceinline__ float fast_tanh(float x) {
    float t = __expf(2.0f * x);
    return 1.0f - 2.0f * __builtin_amdgcn_rcpf(t + 1.0f);
}

// Pack W2 = W[:, H:2H] into bf16, layout Wp[kg][n][8] (kg = k>>3), 16B per (kg,n)
__global__ __launch_bounds__(256) void prep_w_kernel(const float* __restrict__ W,
                                                     unsigned short* __restrict__ Wp) {
    int gid = blockIdx.x * 256 + threadIdx.x;   // 131072 total
    int n = gid & (H - 1);
    int kg = gid >> 10;                          // 0..127
    const float* srcp = W + (size_t)n * (2 * H) + H + kg * 8;
    float4 f0 = *(const float4*)(srcp);
    float4 f1 = *(const float4*)(srcp + 4);
    u16x8 o;
    o[0] = f2bf(f0.x); o[1] = f2bf(f0.y); o[2] = f2bf(f0.z); o[3] = f2bf(f0.w);
    o[4] = f2bf(f1.x); o[5] = f2bf(f1.y); o[6] = f2bf(f1.z); o[7] = f2bf(f1.w);
    *(u16x8*)(Wp + (size_t)gid * 8) = o;
}

// hp[b][h] = sum_d hidden[b][d]*W[h][d] + bias[h], k-split x4 + shuffle reduce
__global__ __launch_bounds__(256) void prep_hp_kernel(const float* __restrict__ hidden,
                                                      const float* __restrict__ W,
                                                      const float* __restrict__ bias,
                                                      float* __restrict__ hp) {
    int b = blockIdx.y;
    int t = threadIdx.x;
    int h = blockIdx.x * 64 + (t >> 2);
    int kq = t & 3;
    const float* hid = hidden + (size_t)b * H + kq * 256;
    const float* wr = W + (size_t)h * (2 * H) + kq * 256;
    float acc = 0.f;
#pragma unroll 4
    for (int d = 0; d < 256; d += 4) {
        float4 wv = *(const float4*)(wr + d);
        float4 hv = *(const float4*)(hid + d);
        acc += wv.x * hv.x + wv.y * hv.y + wv.z * hv.z + wv.w * hv.w;
    }
    acc += __shfl_xor(acc, 1);
    acc += __shfl_xor(acc, 2);
    if (kq == 0) hp[(size_t)b * H + h] = acc + bias[h];
}

#define MFMA32(A, Bv, C) __builtin_amdgcn_mfma_f32_32x32x16_bf16(A, Bv, C, 0, 0, 0)

// Final kernel (best measured config, R10): single fused energy+score pass.
// block = (64-row t-tile, b), 1024 thr = 16 waves; wave w owns cols [64w,64w+64).
// A: enc fp32 read ONCE from HBM, reg-staged (cvt once) -> bf16 LDS, double-buffered;
//    stage-issue at chunk top, ds_write + __syncthreads at chunk end.
// B: Wp bf16 streamed from L2, branchless wrapped depth-2 rolling register prefetch
//    (depth-2 is the L2-friendly optimum; depth-4 and phase-rotation both raised
//    FETCH_SIZE via Wp eviction and regressed).
// LDS layout (measured 0-conflict): page ks (0..15) -> ks*1024 + ((row^(ks&7))<<4).
__global__ __launch_bounds__(1024, 4) void energy_kernel(const float* __restrict__ enc,
                                                         const float* __restrict__ hp,
                                                         const float* __restrict__ vvec,
                                                         const unsigned short* __restrict__ Wp,
                                                         float* __restrict__ scores) {
    __shared__ __align__(16) unsigned short Abuf[2][BM * BKC];  // 2 x 16 KB
    __shared__ float scpart[16][BM];                            // 4 KB

    const int tid = threadIdx.x;
    const int b = blockIdx.y;
    const int t0 = blockIdx.x * BM;
    const int wave = tid >> 6;
    const int lane = tid & 63;
    const int l31 = lane & 31;
    const int hi = lane >> 5;

    // staging: thread -> (row = tid>>4 in 0..63, kf = tid&15); 32B fp32 -> 16B bf16
    const int st_row = tid >> 4;
    const int st_kf = tid & 15;
    const float* st_src = enc + ((size_t)b * T + t0 + st_row) * H + st_kf * 8;
    char* Ab0 = (char*)&Abuf[0][0];
    char* st_dst = Ab0 + st_kf * 1024 + (((st_row ^ (st_kf & 7))) << 4);

    // B stream: k-step nit (0..63): page kg = nit*2 + hi; col = wave*64 + {l31, l31+32}
    const unsigned short* wp_base = Wp + (size_t)(wave * 64 + l31) * 8 + (size_t)hi * (H * 8);

    f32x16 acc00, acc01, acc10, acc11;
#pragma unroll
    for (int i = 0; i < 16; ++i) { acc00[i] = 0.f; acc01[i] = 0.f; acc10[i] = 0.f; acc11[i] = 0.f; }

    const int rv0 = l31;        // a0 rows 0..31
    const int rv1 = 32 + l31;   // a1 rows 32..63

    // ---- prologue: stage chunk 0; preload B nit=0 (A-parity), nit=1 (B-parity) ----
    {
        float4 f0 = *(const float4*)(st_src);
        float4 f1 = *(const float4*)(st_src + 4);
        u16x8 o;
        o[0] = f2bf(f0.x); o[1] = f2bf(f0.y); o[2] = f2bf(f0.z); o[3] = f2bf(f0.w);
        o[4] = f2bf(f1.x); o[5] = f2bf(f1.y); o[6] = f2bf(f1.z); o[7] = f2bf(f1.w);
        *(u16x8*)st_dst = o;
    }
    bf16x8 bA0 = *(const bf16x8*)(wp_base);
    bf16x8 bA1 = *(const bf16x8*)(wp_base + 256);
    bf16x8 bB0 = *(const bf16x8*)(wp_base + (size_t)H * 16);
    bf16x8 bB1 = *(const bf16x8*)(wp_base + (size_t)H * 16 + 256);
    __syncthreads();

    // Rolling invariant: at STEP(KI) of chunk j, regs hold nit = 8j+KI; reload (nit+2)&63
    // (wrap keeps loads unconditional; wrapped loads land after their consumers - harmless).
#define STEP(KI, C0, C1)                                                       \
    {                                                                          \
        const int ks = (KI) * 2 + hi;                                          \
        const char* ap = Ab + ks * 1024;                                       \
        bf16x8 a0 = *(const bf16x8*)(ap + ((rv0 ^ (ks & 7)) << 4));            \
        bf16x8 a1 = *(const bf16x8*)(ap + ((rv1 ^ (ks & 7)) << 4));            \
        __builtin_amdgcn_s_setprio(1);                                         \
        acc00 = MFMA32(a0, C0, acc00);                                         \
        acc01 = MFMA32(a0, C1, acc01);                                         \
        acc10 = MFMA32(a1, C0, acc10);                                         \
        acc11 = MFMA32(a1, C1, acc11);                                         \
        __builtin_amdgcn_s_setprio(0);                                         \
        const int nitw = (j * 8 + (KI) + 2) & 63;                              \
        const unsigned short* bp = wp_base + (size_t)nitw * (H * 16);          \
        C0 = *(const bf16x8*)(bp);                                             \
        C1 = *(const bf16x8*)(bp + 256);                                       \
    }

    for (int j = 0; j < NCHUNK; ++j) {
        // issue next chunk's A loads early (T14: load-early, write-late)
        float4 f0, f1;
        const bool pfA = (j < NCHUNK - 1);
        if (pfA) {
            const float* p = st_src + (j + 1) * BKC;
            f0 = *(const float4*)(p);
            f1 = *(const float4*)(p + 4);
        }
        const char* Ab = Ab0 + (j & 1) * 16384;
        STEP(0, bA0, bA1)
        STEP(1, bB0, bB1)
        STEP(2, bA0, bA1)
        STEP(3, bB0, bB1)
        STEP(4, bA0, bA1)
        STEP(5, bB0, bB1)
        STEP(6, bA0, bA1)
        STEP(7, bB0, bB1)
        if (pfA) {
            u16x8 o;
            o[0] = f2bf(f0.x); o[1] = f2bf(f0.y); o[2] = f2bf(f0.z); o[3] = f2bf(f0.w);
            o[4] = f2bf(f1.x); o[5] = f2bf(f1.y); o[6] = f2bf(f1.z); o[7] = f2bf(f1.w);
            *(u16x8*)(st_dst + ((j + 1) & 1) * 16384) = o;
        }
        __syncthreads();
    }
#undef STEP

    // ---- fused epilogue: tanh + v-dot over this wave's 64 cols ----
    const size_t bH = (size_t)b * H;
    const int col0 = wave * 64 + l31;
    const int col1 = col0 + 32;
    const float hp0 = hp[bH + col0], hp1 = hp[bH + col1];
    const float v0 = vvec[col0], v1 = vvec[col1];
    float psc[2][16];
#pragma unroll
    for (int r = 0; r < 16; ++r) {
        psc[0][r] = v0 * fast_tanh(acc00[r] + hp0) + v1 * fast_tanh(acc01[r] + hp1);
        psc[1][r] = v0 * fast_tanh(acc10[r] + hp0) + v1 * fast_tanh(acc11[r] + hp1);
    }

#pragma unroll
    for (int rg = 0; rg < 2; ++rg)
#pragma unroll
        for (int r = 0; r < 16; ++r) {
            float s = psc[rg][r];
            s += __shfl_xor(s, 1);
            s += __shfl_xor(s, 2);
            s += __shfl_xor(s, 4);
            s += __shfl_xor(s, 8);
            s += __shfl_xor(s, 16);
            psc[rg][r] = s;
        }
    if (l31 == 0) {
#pragma unroll
        for (int rg = 0; rg < 2; ++rg)
#pragma unroll
            for (int r = 0; r < 16; ++r) {
                int m = rg * 32 + (r & 3) + 8 * (r >> 2) + 4 * hi;
                scpart[wave][m] = psc[rg][r];
            }
    }
    __syncthreads();
    if (tid < BM) {
        float s = 0.f;
#pragma unroll
        for (int w = 0; w < 16; ++w) s += scpart[w][tid];
        scores[(size_t)b * T + t0 + tid] = s;
    }
}

__global__ __launch_bounds__(256) void softmax_kernel(const float* __restrict__ sc,
                                                      float* __restrict__ out) {
    int b = blockIdx.x;
    int tid = threadIdx.x;
    int wave = tid >> 6, lane = tid & 63;
    const float* row = sc + (size_t)b * T;
    float vals[8];
    float m = -1e30f;
#pragma unroll
    for (int i = 0; i < 8; ++i) { vals[i] = row[tid + 256 * i]; m = fmaxf(m, vals[i]); }
#pragma unroll
    for (int s = 1; s < 64; s <<= 1) m = fmaxf(m, __shfl_xor(m, s));
    __shared__ float red[4];
    __shared__ float red2[4];
    if (lane == 0) red[wave] = m;
    __syncthreads();
    m = fmaxf(fmaxf(red[0], red[1]), fmaxf(red[2], red[3]));
    float sum = 0.f;
#pragma unroll
    for (int i = 0; i < 8; ++i) { vals[i] = expf(vals[i] - m); sum += vals[i]; }
#pragma unroll
    for (int s = 1; s < 64; s <<= 1) sum += __shfl_xor(sum, s);
    if (lane == 0) red2[wave] = sum;
    __syncthreads();
    sum = red2[0] + red2[1] + red2[2] + red2[3];
    float inv = 1.0f / sum;
#pragma unroll
    for (int i = 0; i < 8; ++i) out[(size_t)b * T + tid + 256 * i] = vals[i] * inv;
}

extern "C" void kernel_launch(void* const* d_in, const int* in_sizes, int n_in,
                              void* d_out, int out_size, void* d_ws, size_t ws_size,
                              hipStream_t stream) {
    (void)in_sizes; (void)n_in; (void)out_size; (void)ws_size;
    const float* hidden = (const float*)d_in[0];   // [1,B,H]
    const float* enc    = (const float*)d_in[1];   // [B,T,H]
    const float* W      = (const float*)d_in[2];   // [H,2H]
    const float* bias   = (const float*)d_in[3];   // [H]
    const float* v      = (const float*)d_in[4];   // [H]
    float* out = (float*)d_out;                    // [B,1,T]

    unsigned short* Wp = (unsigned short*)d_ws;                               // 2 MB
    float* hp = (float*)((char*)d_ws + 2 * 1024 * 1024);                      // 128 KB
    float* sc = (float*)((char*)d_ws + 2 * 1024 * 1024 + 128 * 1024);         // 256 KB

    prep_w_kernel<<<dim3(512), dim3(256), 0, stream>>>(W, Wp);
    prep_hp_kernel<<<dim3(16, B), dim3(256), 0, stream>>>(hidden, W, bias, hp);
    energy_kernel<<<dim3(T / BM, B), dim3(1024), 0, stream>>>(enc, hp, v, Wp, sc);
    softmax_kernel<<<dim3(B), dim3(256), 0, stream>>>(sc, out);
}